// Round 6
// baseline (197.209 us; speedup 1.0000x reference)
//
#include <hip/hip_runtime.h>
#include <hip/hip_bf16.h>

// CenterWoParamsLoss: loss = sum((x - centers[labels])^2) / 2 / BATCH
// x: (16384, 2048) fp32, labels: (16384,) int32, centers: (1000, 2048) fp32.
//
// Structure: row-per-block. Each 512-thread block owns 8 rows; thread t owns
// float4-column t (512 cols exactly). labels[r0..r0+7] are block-uniform ->
// scalar s_load (no per-lane dependent gather). x loaded nontemporal so the
// 128 MiB stream doesn't evict centers (8 MiB, half fits per 4 MiB XCD L2).
// Floor: ~136 MiB / 6.85 TB/s (fill-kernel-measured ceiling) ~= 20 us.

#define CL_BATCH 16384
#define CL_FEAT  2048
#define CL_F4    512                 // float4 per row
#define CL_TPB   512                 // 8 waves; one thread per f4-column
#define CL_RPB   8                   // rows per block
#define CL_NBLK  (CL_BATCH / CL_RPB) // 2048 blocks / partials

typedef float f32x4 __attribute__((ext_vector_type(4)));

__global__ __launch_bounds__(CL_TPB) void center_loss_partial_kernel(
    const float* __restrict__ x,
    const int* __restrict__ labels,
    const float* __restrict__ centers,
    float* __restrict__ partial) {
  const f32x4* __restrict__ x4 = reinterpret_cast<const f32x4*>(x);
  const f32x4* __restrict__ c4 = reinterpret_cast<const f32x4*>(centers);

  const int r0 = blockIdx.x * CL_RPB;   // block-uniform
  const int t  = threadIdx.x;           // f4-column, 0..511

  // Block-uniform label loads -> scalar pipe (s_load_dwordx8), one wait.
  int lab[CL_RPB];
  #pragma unroll
  for (int k = 0; k < CL_RPB; ++k) lab[k] = labels[r0 + k];

  float acc = 0.0f;
  #pragma unroll
  for (int k = 0; k < CL_RPB; ++k) {
    // x: streaming, read-once -> nontemporal (don't pollute L2).
    f32x4 xv = __builtin_nontemporal_load(&x4[(size_t)(r0 + k) * CL_F4 + t]);
    // centers: reused across the whole batch -> normal cached load.
    f32x4 cv = c4[(size_t)lab[k] * CL_F4 + t];
    f32x4 d = xv - cv;
    acc += d.x * d.x + d.y * d.y + d.z * d.z + d.w * d.w;
  }

  // wave-64 butterfly reduce
  #pragma unroll
  for (int off = 32; off > 0; off >>= 1)
    acc += __shfl_down(acc, off, 64);

  __shared__ float lds[CL_TPB / 64];
  int wave = threadIdx.x >> 6;
  int lane = threadIdx.x & 63;
  if (lane == 0) lds[wave] = acc;
  __syncthreads();
  if (threadIdx.x == 0) {
    float s = 0.0f;
    #pragma unroll
    for (int w = 0; w < CL_TPB / 64; ++w) s += lds[w];
    partial[blockIdx.x] = s;
  }
}

__global__ __launch_bounds__(256) void center_loss_reduce_kernel(
    const float* __restrict__ partial, float* __restrict__ out) {
  float acc = 0.0f;
  for (int i = threadIdx.x; i < CL_NBLK; i += 256) acc += partial[i];
  #pragma unroll
  for (int off = 32; off > 0; off >>= 1)
    acc += __shfl_down(acc, off, 64);

  __shared__ float lds[4];
  int wave = threadIdx.x >> 6;
  int lane = threadIdx.x & 63;
  if (lane == 0) lds[wave] = acc;
  __syncthreads();
  if (threadIdx.x == 0) {
    float s = 0.0f;
    #pragma unroll
    for (int w = 0; w < 4; ++w) s += lds[w];
    out[0] = s * (0.5f / (float)CL_BATCH);
  }
}

extern "C" void kernel_launch(void* const* d_in, const int* in_sizes, int n_in,
                              void* d_out, int out_size, void* d_ws, size_t ws_size,
                              hipStream_t stream) {
  const float* x       = (const float*)d_in[0];
  const int*   labels  = (const int*)d_in[1];
  const float* centers = (const float*)d_in[2];
  float* out     = (float*)d_out;
  float* partial = (float*)d_ws;   // CL_NBLK floats = 8 KiB of scratch

  center_loss_partial_kernel<<<CL_NBLK, CL_TPB, 0, stream>>>(x, labels, centers, partial);
  center_loss_reduce_kernel<<<1, 256, 0, stream>>>(partial, out);
}

// Round 10
// 196.025 us; speedup vs baseline: 1.0060x; 1.0060x over previous
//
#include <hip/hip_runtime.h>
#include <hip/hip_bf16.h>

// CenterWoParamsLoss: loss = sum((x - centers[labels])^2) / 2 / BATCH
// x: (16384, 2048) fp32, labels: (16384,) int32, centers: (1000, 2048) fp32.
//
// R7: ILP-depth probe. 256 threads/block, each thread owns f4-columns
// {t, t+256} of 8 rows -> 32 independent loads in flight per thread
// (16 nt x-loads + 16 cached c-loads), fully unrolled, labels scalar.
// If the kernel was latency-bound (L3-hit centers gather), this doubles
// outstanding loads and should cut its time; if it was already at the
// ~21 us BW floor, total dur_us stays ~197 (overhead-dominated).

#define CL_BATCH 16384
#define CL_FEAT  2048
#define CL_F4    512                 // float4 per row
#define CL_TPB   256
#define CL_CPT   2                   // f4-columns per thread
#define CL_RPB   8                   // rows per block
#define CL_NBLK  (CL_BATCH / CL_RPB) // 2048 blocks / partials

typedef float f32x4 __attribute__((ext_vector_type(4)));

__global__ __launch_bounds__(CL_TPB) void center_loss_partial_kernel(
    const float* __restrict__ x,
    const int* __restrict__ labels,
    const float* __restrict__ centers,
    float* __restrict__ partial) {
  const f32x4* __restrict__ x4 = reinterpret_cast<const f32x4*>(x);
  const f32x4* __restrict__ c4 = reinterpret_cast<const f32x4*>(centers);

  const int r0 = blockIdx.x * CL_RPB;   // block-uniform
  const int t  = threadIdx.x;           // 0..255; owns cols t and t+256

  // Block-uniform label loads -> scalar pipe, one wait.
  int lab[CL_RPB];
  #pragma unroll
  for (int k = 0; k < CL_RPB; ++k) lab[k] = labels[r0 + k];

  // Issue all 32 loads (static-indexed arrays -> registers, rule #20).
  f32x4 xv[CL_RPB][CL_CPT], cv[CL_RPB][CL_CPT];
  #pragma unroll
  for (int k = 0; k < CL_RPB; ++k) {
    #pragma unroll
    for (int c = 0; c < CL_CPT; ++c) {
      int col = t + c * CL_TPB;
      xv[k][c] = __builtin_nontemporal_load(
          &x4[(size_t)(r0 + k) * CL_F4 + col]);   // streaming, read-once
      cv[k][c] = c4[(size_t)lab[k] * CL_F4 + col]; // cache-resident reuse
    }
  }

  float acc = 0.0f;
  #pragma unroll
  for (int k = 0; k < CL_RPB; ++k) {
    #pragma unroll
    for (int c = 0; c < CL_CPT; ++c) {
      f32x4 d = xv[k][c] - cv[k][c];
      acc += d.x * d.x + d.y * d.y + d.z * d.z + d.w * d.w;
    }
  }

  // wave-64 butterfly reduce
  #pragma unroll
  for (int off = 32; off > 0; off >>= 1)
    acc += __shfl_down(acc, off, 64);

  __shared__ float lds[CL_TPB / 64];
  int wave = threadIdx.x >> 6;
  int lane = threadIdx.x & 63;
  if (lane == 0) lds[wave] = acc;
  __syncthreads();
  if (threadIdx.x == 0) {
    float s = 0.0f;
    #pragma unroll
    for (int w = 0; w < CL_TPB / 64; ++w) s += lds[w];
    partial[blockIdx.x] = s;
  }
}

__global__ __launch_bounds__(256) void center_loss_reduce_kernel(
    const float* __restrict__ partial, float* __restrict__ out) {
  float acc = 0.0f;
  for (int i = threadIdx.x; i < CL_NBLK; i += 256) acc += partial[i];
  #pragma unroll
  for (int off = 32; off > 0; off >>= 1)
    acc += __shfl_down(acc, off, 64);

  __shared__ float lds[4];
  int wave = threadIdx.x >> 6;
  int lane = threadIdx.x & 63;
  if (lane == 0) lds[wave] = acc;
  __syncthreads();
  if (threadIdx.x == 0) {
    float s = 0.0f;
    #pragma unroll
    for (int w = 0; w < 4; ++w) s += lds[w];
    out[0] = s * (0.5f / (float)CL_BATCH);
  }
}

extern "C" void kernel_launch(void* const* d_in, const int* in_sizes, int n_in,
                              void* d_out, int out_size, void* d_ws, size_t ws_size,
                              hipStream_t stream) {
  const float* x       = (const float*)d_in[0];
  const int*   labels  = (const int*)d_in[1];
  const float* centers = (const float*)d_in[2];
  float* out     = (float*)d_out;
  float* partial = (float*)d_ws;   // CL_NBLK floats = 8 KiB of scratch

  center_loss_partial_kernel<<<CL_NBLK, CL_TPB, 0, stream>>>(x, labels, centers, partial);
  center_loss_reduce_kernel<<<1, 256, 0, stream>>>(partial, out);
}